// Round 1
// baseline (895.270 us; speedup 1.0000x reference)
//
#include <hip/hip_runtime.h>
#include <hip/hip_bf16.h>

// ---------------------------------------------------------------------------
// TransportOperator: FISTA sparse coding through block-diag expm + transport.
// B=256, D=512, K=8, M=64, N=64.  20 FISTA iters, lr=0.01, lambda=0.05.
//
// R12 = R6 champion structure with krylov rewritten barrier-free:
//   gemm1 (1024 wgs): T = y*psi, MFMA, swizzled LDS-transpose epilogue.
//   krylov<5,1> (512 wgs, 1 wave per (b,k)): T row/col in regs, matvec
//     broadcasts via v_readlane (VALU pipe, ZERO LDS, ZERO barriers).
//   gemm2 (256 wgs): 64 split-K fp32 partials, MFMA, parallel 4-wave LDS
//     partials + single barrier reduce (was 4-barrier serialized).
//   fista (64 wgs): reduce 64 partials + prox; writes fp32 state + bf16 y/c.
// Final: gemm1 + krylov<8,0> apply.
// ---------------------------------------------------------------------------

typedef __attribute__((ext_vector_type(8))) short bf16x8;
typedef __attribute__((ext_vector_type(4))) float f32x4;
typedef unsigned short ushort_t;
typedef unsigned int uint_t;

__device__ __constant__ float INVF[20] = {
    1.0f, 1.0f, 0.5f, 1.6666666666666666e-1f, 4.1666666666666664e-2f,
    8.333333333333333e-3f, 1.3888888888888889e-3f, 1.984126984126984e-4f,
    2.48015873015873e-5f, 2.7557319223985893e-6f, 2.755731922398589e-7f,
    2.505210838544172e-8f, 2.08767569878681e-9f, 1.6059043836821613e-10f,
    1.1470745597729725e-11f, 7.647163731819816e-13f, 4.779477332387385e-14f,
    2.8114572543455206e-15f, 1.5619206968586225e-16f, 8.22063524662433e-18f};

__device__ __forceinline__ ushort_t f2b(float x) {
    uint_t u = __float_as_uint(x);
    uint_t r = u + 0x7FFFu + ((u >> 16) & 1u);   // RNE
    return (ushort_t)(r >> 16);
}
__device__ __forceinline__ float b2f(ushort_t h) {
    return __uint_as_float((uint_t)h << 16);
}
__device__ __forceinline__ float rdlane(float v, int l) {
    return __int_as_float(__builtin_amdgcn_readlane(__float_as_int(v), l));
}

// --- one-time: psi -> psiB [k][m][uv], psiT [j][m]; zero c/y state ---------
__global__ __launch_bounds__(256) void prep_k(const float* __restrict__ psi,
                                              ushort_t* __restrict__ psiB,
                                              ushort_t* __restrict__ psiT,
                                              uint4* __restrict__ zero_base) {
    if (blockIdx.x < 48)   // zero 48*256*16 B = 196608 B (c,y fp32 + bf16)
        zero_base[blockIdx.x * 256 + threadIdx.x] = make_uint4(0, 0, 0, 0);
    int base = blockIdx.x * 2048 + threadIdx.x;
    for (int i = 0; i < 8; ++i) {
        int e = base + i * 256;                // e in [0, 2097152)
        float v = psi[e];
        ushort_t h = f2b(v);
        psiB[e] = h;
        int k = e >> 18;
        int r = e & 262143;
        int m = r >> 12;
        int uv = r & 4095;
        psiT[(size_t)k * 262144 + (size_t)uv * 64 + m] = h;
    }
}

// --- GEMM1: T[b][j] = sum_m y[b,m] * psiT[j,m].  D-rows <-> j. -------------
// grid 1024 = 512 j-windows x 2 b-halves (128 b).  18 KB LDS.
__global__ __launch_bounds__(256) void gemm1_k(const ushort_t* __restrict__ ybf,
                                               const ushort_t* __restrict__ psiT,
                                               ushort_t* __restrict__ Tbf) {
    __shared__ __align__(16) ushort_t Ls[128 * 72];   // [b 128][j 64] swizzled
    int wg = blockIdx.x;
    int j0 = (wg & 511) * 64;
    int bt = wg >> 9;                   // 0..1
    int tid = threadIdx.x;
    int wave = tid >> 6, lane = tid & 63;
    int rowi = lane & 15, q = lane >> 4;
    int b0w = bt * 128 + wave * 32;

    f32x4 acc[4][2];
    const f32x4 zero = {0.f, 0.f, 0.f, 0.f};
    for (int ta = 0; ta < 4; ++ta)
        for (int tb = 0; tb < 2; ++tb) acc[ta][tb] = zero;

    for (int ks = 0; ks < 2; ++ks) {
        bf16x8 a[4], bb[2];
        for (int ta = 0; ta < 4; ++ta)
            a[ta] = *(const bf16x8*)(psiT + (size_t)(j0 + ta * 16 + rowi) * 64 +
                                     ks * 32 + q * 8);
        for (int tb = 0; tb < 2; ++tb)
            bb[tb] = *(const bf16x8*)(ybf + (size_t)(b0w + tb * 16 + rowi) * 64 +
                                      ks * 32 + q * 8);
        for (int ta = 0; ta < 4; ++ta)
            for (int tb = 0; tb < 2; ++tb)
                acc[ta][tb] = __builtin_amdgcn_mfma_f32_16x16x32_bf16(
                    a[ta], bb[tb], acc[ta][tb], 0, 0, 0);
    }
    for (int ta = 0; ta < 4; ++ta)
        for (int tb = 0; tb < 2; ++tb) {
            int bl = wave * 32 + tb * 16 + rowi;      // local b in [0,128)
            int jl = ta * 16 + q * 4;
            uint_t lo = (uint_t)f2b(acc[ta][tb][0]) | ((uint_t)f2b(acc[ta][tb][1]) << 16);
            uint_t hi = (uint_t)f2b(acc[ta][tb][2]) | ((uint_t)f2b(acc[ta][tb][3]) << 16);
            int idx = bl * 72 + ((((jl >> 3) + 2 * bl) & 7) << 3) + (jl & 7);
            *(uint2*)&Ls[idx] = make_uint2(lo, hi);
        }
    __syncthreads();
    for (int pass = 0; pass < 4; ++pass) {
        int b = pass * 32 + (tid >> 3);               // local b
        int ch = tid & 7;
        uint4 v = *(const uint4*)&Ls[b * 72 + ch * 8];
        int x = (ch - 2 * b) & 7;
        *(uint4*)(Tbf + (size_t)(bt * 128 + b) * 32768 + j0 + x * 8) = v;
    }
}

// --- Krylov: one wave per (b,k); all state in registers; NO LDS/barriers. --
// Broadcast of the wave-uniform v-vector elements via v_readlane (VALU pipe).
// GRAD=1: writes O = sum_l W_l V_l^T over T.  GRAD=0: writes zhat to out.
template <int NT, int GRAD>
__global__ __launch_bounds__(256) void krylov_k(ushort_t* __restrict__ Tbf,
                                                const float* __restrict__ z0,
                                                const float* __restrict__ z1,
                                                float* __restrict__ out) {
    int lane = threadIdx.x & 63;
    int bid = blockIdx.x * 4 + (threadIdx.x >> 6);   // (b,k) pair
    int b = bid >> 3, k = bid & 7;
    ushort_t* tbase = Tbf + (size_t)bid * 4096;

    // lane r owns row r of T: 64 bf16 = 8 x uint4 (16B per lane, 128B stride)
    float rowT[64];
    {
        const uint4* tp = (const uint4*)(tbase + (size_t)lane * 64);
#pragma unroll
        for (int cc = 0; cc < 8; ++cc) {
            uint4 v = tp[cc];
            uint_t w[4] = {v.x, v.y, v.z, v.w};
#pragma unroll
            for (int i = 0; i < 4; ++i) {
                rowT[cc * 8 + 2 * i]     = __uint_as_float(w[i] << 16);
                rowT[cc * 8 + 2 * i + 1] = __uint_as_float(w[i] & 0xFFFF0000u);
            }
        }
    }

    float vs[NT];
    vs[0] = z0[(size_t)b * 512 + k * 64 + lane];
#pragma unroll
    for (int l = 1; l < NT; ++l) {
        float sp = vs[l - 1];
        float a0 = 0.f, a1 = 0.f, a2 = 0.f, a3 = 0.f;
#pragma unroll
        for (int i = 0; i < 64; i += 4) {
            a0 = fmaf(rowT[i],     rdlane(sp, i),     a0);
            a1 = fmaf(rowT[i + 1], rdlane(sp, i + 1), a1);
            a2 = fmaf(rowT[i + 2], rdlane(sp, i + 2), a2);
            a3 = fmaf(rowT[i + 3], rdlane(sp, i + 3), a3);
        }
        vs[l] = (a0 + a1) + (a2 + a3);
    }

    float zh = 0.f;
#pragma unroll
    for (int l = 0; l < NT; ++l) zh = fmaf(INVF[l], vs[l], zh);

    if constexpr (!GRAD) {
        out[(size_t)b * 512 + k * 64 + lane] = zh;
        return;
    } else {
        // lane c owns column c of T (coalesced 128B per instruction, L1-hot)
        float colT[64];
#pragma unroll
        for (int i = 0; i < 64; ++i)
            colT[i] = b2f(tbase[(size_t)i * 64 + lane]);

        float us[NT];
        us[0] = zh - z1[(size_t)b * 512 + k * 64 + lane];
#pragma unroll
        for (int j = 1; j < NT; ++j) {
            float sp = us[j - 1];
            float a0 = 0.f, a1 = 0.f, a2 = 0.f, a3 = 0.f;
#pragma unroll
            for (int i = 0; i < 64; i += 4) {
                a0 = fmaf(colT[i],     rdlane(sp, i),     a0);
                a1 = fmaf(colT[i + 1], rdlane(sp, i + 1), a1);
                a2 = fmaf(colT[i + 2], rdlane(sp, i + 2), a2);
                a3 = fmaf(colT[i + 3], rdlane(sp, i + 3), a3);
            }
            us[j] = (a0 + a1) + (a2 + a3);
        }

        float W[NT];
#pragma unroll
        for (int l = 0; l < NT; ++l) {
            float w = 0.f;
#pragma unroll
            for (int j = 0; j < NT; ++j) w = fmaf(INVF[j + l + 1], us[j], w);
            W[l] = w;
        }

        // O[lane][c] = sum_l W[l](per-lane) * V_l[c](wave-uniform scalar)
        float o[64];
#pragma unroll
        for (int c = 0; c < 64; ++c) o[c] = 0.f;
#pragma unroll
        for (int l = 0; l < NT; ++l) {
            float wl = W[l];
#pragma unroll
            for (int c = 0; c < 64; ++c)
                o[c] = fmaf(wl, rdlane(vs[l], c), o[c]);
        }

        uint4* op = (uint4*)(tbase + (size_t)lane * 64);
#pragma unroll
        for (int cc = 0; cc < 8; ++cc) {
            uint_t w0 = (uint_t)f2b(o[cc * 8 + 0]) | ((uint_t)f2b(o[cc * 8 + 1]) << 16);
            uint_t w1 = (uint_t)f2b(o[cc * 8 + 2]) | ((uint_t)f2b(o[cc * 8 + 3]) << 16);
            uint_t w2 = (uint_t)f2b(o[cc * 8 + 4]) | ((uint_t)f2b(o[cc * 8 + 5]) << 16);
            uint_t w3 = (uint_t)f2b(o[cc * 8 + 6]) | ((uint_t)f2b(o[cc * 8 + 7]) << 16);
            op[cc] = make_uint4(w0, w1, w2, w3);
        }
    }
}

// --- GEMM2: gpart[kc][b][m] = sum_{uv in chunk} O[b][.] psiB[m][.] ---------
// grid 256 = 4 bt x 64 kc; 4 waves split the 512-long K-chunk.
// Parallel per-wave LDS partials + ONE barrier (was 4-barrier serialized).
__global__ __launch_bounds__(256) void gemm2_k(const ushort_t* __restrict__ Obf,
                                               const ushort_t* __restrict__ psiB,
                                               float* __restrict__ gpart) {
    __shared__ __align__(16) float Lg[4][64 * 68];    // 69.6 KB, [w][b][m]
    int bt = blockIdx.x & 3;
    int kc = blockIdx.x >> 2;          // 0..63
    int k = kc >> 3;
    int uv0 = (kc & 7) * 512;
    int tid = threadIdx.x, wave = tid >> 6, lane = tid & 63;
    int rowi = lane & 15, q = lane >> 4;

    f32x4 acc[4][4];
    const f32x4 zero = {0.f, 0.f, 0.f, 0.f};
    for (int ta = 0; ta < 4; ++ta)
        for (int tb = 0; tb < 4; ++tb) acc[ta][tb] = zero;

    for (int ks = 0; ks < 4; ++ks) {
        int off = uv0 + wave * 128 + ks * 32 + q * 8;
        bf16x8 a[4], bb[4];
        for (int ta = 0; ta < 4; ++ta)
            a[ta] = *(const bf16x8*)(psiB + (size_t)k * 262144 +
                                     (size_t)(ta * 16 + rowi) * 4096 + off);
        for (int tb = 0; tb < 4; ++tb)
            bb[tb] = *(const bf16x8*)(Obf +
                                      (size_t)(bt * 64 + tb * 16 + rowi) * 32768 +
                                      k * 4096 + off);
        for (int ta = 0; ta < 4; ++ta)
            for (int tb = 0; tb < 4; ++tb)
                acc[ta][tb] = __builtin_amdgcn_mfma_f32_16x16x32_bf16(
                    a[ta], bb[tb], acc[ta][tb], 0, 0, 0);
    }
    float* lw = &Lg[wave][0];
    for (int ta = 0; ta < 4; ++ta)
        for (int tb = 0; tb < 4; ++tb)
            *(f32x4*)&lw[(tb * 16 + rowi) * 68 + ta * 16 + q * 4] = acc[ta][tb];
    __syncthreads();

    int b = tid >> 2, mq = tid & 3;
    const float* l0 = &Lg[0][b * 68 + mq * 16];
    float* gp = gpart + (size_t)kc * 16384 + (size_t)(bt * 64 + b) * 64 + mq * 16;
#pragma unroll
    for (int i = 0; i < 4; ++i) {
        f32x4 s0 = *(const f32x4*)(l0 + 4 * i);
        f32x4 s1 = *(const f32x4*)(l0 + 4352 + 4 * i);
        f32x4 s2 = *(const f32x4*)(l0 + 8704 + 4 * i);
        f32x4 s3 = *(const f32x4*)(l0 + 13056 + 4 * i);
        f32x4 s = (s0 + s1) + (s2 + s3);
        *(f32x4*)(gp + 4 * i) = s;
    }
}

// --- FISTA: reduce 64 partials + prox step; maintain fp32 + bf16 state -----
__global__ __launch_bounds__(256) void fista_update(const float* __restrict__ gpart,
                                                    float* __restrict__ cb,
                                                    float* __restrict__ yb,
                                                    ushort_t* __restrict__ cbf,
                                                    ushort_t* __restrict__ ybf,
                                                    int iter) {
    int idx = blockIdx.x * 256 + threadIdx.x;
    float a0 = 0.f, a1 = 0.f, a2 = 0.f, a3 = 0.f;
#pragma unroll
    for (int p = 0; p < 64; p += 4) {
        a0 += gpart[(size_t)p * 16384 + idx];
        a1 += gpart[(size_t)(p + 1) * 16384 + idx];
        a2 += gpart[(size_t)(p + 2) * 16384 + idx];
        a3 += gpart[(size_t)(p + 3) * 16384 + idx];
    }
    float gv = (a0 + a1) + (a2 + a3);
    float t = 1.f;
    for (int s = 0; s < iter; ++s) t = 0.5f * (1.f + sqrtf(1.f + 4.f * t * t));
    float tn = 0.5f * (1.f + sqrtf(1.f + 4.f * t * t));
    float beta = (t - 1.f) / tn;
    float co = cb[idx], yo = yb[idx];
    float a = yo - 0.01f * gv;
    float thr = 0.01f * 0.05f;
    float cn = copysignf(fmaxf(fabsf(a) - thr, 0.f), a);
    float yn = cn + beta * (cn - co);
    cb[idx] = cn;
    yb[idx] = yn;
    cbf[idx] = f2b(cn);
    ybf[idx] = f2b(yn);
}

extern "C" void kernel_launch(void* const* d_in, const int* in_sizes, int n_in,
                              void* d_out, int out_size, void* d_ws, size_t ws_size,
                              hipStream_t stream) {
    const float* z0 = (const float*)d_in[0];
    const float* z1 = (const float*)d_in[1];
    const float* psi = (const float*)d_in[2];
    float* out = (float*)d_out;

    char* w = (char*)d_ws;
    ushort_t* TO    = (ushort_t*)(w);                 // 16,777,216  (T, then O)
    ushort_t* psiB  = (ushort_t*)(w + 16777216);      //  4,194,304
    ushort_t* psiT  = (ushort_t*)(w + 20971520);      //  4,194,304
    float*    gpart = (float*)(w + 25165824);         //  4,194,304  (64 partials)
    float*    cbuf  = (float*)(w + 29360128);         //     65,536
    float*    ybuf  = (float*)(w + 29425664);         //     65,536
    ushort_t* cbf   = (ushort_t*)(w + 29491200);      //     32,768
    ushort_t* ybf   = (ushort_t*)(w + 29523968);      //     32,768
    // total 29,556,736 B

    // prep converts psi AND zeroes c/y state (196608 B) -- no memset node
    prep_k<<<1024, 256, 0, stream>>>(psi, psiB, psiT, (uint4*)(w + 29360128));

    for (int it = 0; it < 20; ++it) {
        gemm1_k<<<1024, 256, 0, stream>>>(ybf, psiT, TO);
        krylov_k<5, 1><<<512, 256, 0, stream>>>(TO, z0, z1, nullptr);
        gemm2_k<<<256, 256, 0, stream>>>(TO, psiB, gpart);
        fista_update<<<64, 256, 0, stream>>>(gpart, cbuf, ybuf, cbf, ybf, it);
    }

    gemm1_k<<<1024, 256, 0, stream>>>(cbf, psiT, TO);
    krylov_k<8, 0><<<512, 256, 0, stream>>>(TO, z0, z1, out);
}

// Round 2
// 864.264 us; speedup vs baseline: 1.0359x; 1.0359x over previous
//
#include <hip/hip_runtime.h>
#include <hip/hip_bf16.h>

// ---------------------------------------------------------------------------
// TransportOperator: FISTA sparse coding through block-diag expm + transport.
// B=256, D=512, K=8, M=64, N=64.  20 FISTA iters, lr=0.01, lambda=0.05.
//
// R13 = R6 champion structure (krylov reverted verbatim after R12's readlane
// rewrite regressed: readlane broadcast doubles VALU work vs LDS+barrier).
//   gemm1 (1024 wgs): T = y*psi, MFMA, swizzled LDS-transpose epilogue.
//   krylov<5> (2048 wgs): per-(b,k), T in regs, DPP quad-reduce, O over T.
//   gemm2 (512 wgs, was 256): 8-way b-split x 64 kc -> 2 wg/CU, 8 waves/CU
//     (was 1 wg/CU latency-bound); parallel per-wave LDS partials + ONE
//     barrier reduce (was 4-barrier serialized).
//   fista (64 wgs): reduce 64 partials + prox; writes fp32 state + bf16 y/c.
// Final: gemm1 + krylov<8> apply.
// ---------------------------------------------------------------------------

typedef __attribute__((ext_vector_type(8))) short bf16x8;
typedef __attribute__((ext_vector_type(4))) float f32x4;
typedef unsigned short ushort_t;
typedef unsigned int uint_t;

__device__ __constant__ float INVF[20] = {
    1.0f, 1.0f, 0.5f, 1.6666666666666666e-1f, 4.1666666666666664e-2f,
    8.333333333333333e-3f, 1.3888888888888889e-3f, 1.984126984126984e-4f,
    2.48015873015873e-5f, 2.7557319223985893e-6f, 2.755731922398589e-7f,
    2.505210838544172e-8f, 2.08767569878681e-9f, 1.6059043836821613e-10f,
    1.1470745597729725e-11f, 7.647163731819816e-13f, 4.779477332387385e-14f,
    2.8114572543455206e-15f, 1.5619206968586225e-16f, 8.22063524662433e-18f};

__device__ __forceinline__ ushort_t f2b(float x) {
    uint_t u = __float_as_uint(x);
    uint_t r = u + 0x7FFFu + ((u >> 16) & 1u);   // RNE
    return (ushort_t)(r >> 16);
}
__device__ __forceinline__ float b2f(ushort_t h) {
    return __uint_as_float((uint_t)h << 16);
}

// quad sum via DPP (VALU pipe, no LDS ops)
__device__ __forceinline__ float qsum4(float s) {
    int a = __builtin_amdgcn_update_dpp(0, __float_as_int(s), 0xB1, 0xF, 0xF, true);
    s += __int_as_float(a);                       // xor 1
    int b = __builtin_amdgcn_update_dpp(0, __float_as_int(s), 0x4E, 0xF, 0xF, true);
    s += __int_as_float(b);                       // xor 2
    return s;
}

// --- one-time: psi -> psiB [k][m][uv], psiT [j][m]; zero c/y state ---------
__global__ __launch_bounds__(256) void prep_k(const float* __restrict__ psi,
                                              ushort_t* __restrict__ psiB,
                                              ushort_t* __restrict__ psiT,
                                              uint4* __restrict__ zero_base) {
    if (blockIdx.x < 48)   // zero 48*256*16 B = 196608 B (c,y fp32 + bf16)
        zero_base[blockIdx.x * 256 + threadIdx.x] = make_uint4(0, 0, 0, 0);
    int base = blockIdx.x * 2048 + threadIdx.x;
    for (int i = 0; i < 8; ++i) {
        int e = base + i * 256;                // e in [0, 2097152)
        float v = psi[e];
        ushort_t h = f2b(v);
        psiB[e] = h;
        int k = e >> 18;
        int r = e & 262143;
        int m = r >> 12;
        int uv = r & 4095;
        psiT[(size_t)k * 262144 + (size_t)uv * 64 + m] = h;
    }
}

// --- GEMM1: T[b][j] = sum_m y[b,m] * psiT[j,m].  D-rows <-> j. -------------
// grid 1024 = 512 j-windows x 2 b-halves (128 b).  18 KB LDS.
__global__ __launch_bounds__(256) void gemm1_k(const ushort_t* __restrict__ ybf,
                                               const ushort_t* __restrict__ psiT,
                                               ushort_t* __restrict__ Tbf) {
    __shared__ __align__(16) ushort_t Ls[128 * 72];   // [b 128][j 64] swizzled
    int wg = blockIdx.x;
    int j0 = (wg & 511) * 64;
    int bt = wg >> 9;                   // 0..1
    int tid = threadIdx.x;
    int wave = tid >> 6, lane = tid & 63;
    int rowi = lane & 15, q = lane >> 4;
    int b0w = bt * 128 + wave * 32;

    f32x4 acc[4][2];
    const f32x4 zero = {0.f, 0.f, 0.f, 0.f};
    for (int ta = 0; ta < 4; ++ta)
        for (int tb = 0; tb < 2; ++tb) acc[ta][tb] = zero;

    for (int ks = 0; ks < 2; ++ks) {
        bf16x8 a[4], bb[2];
        for (int ta = 0; ta < 4; ++ta)
            a[ta] = *(const bf16x8*)(psiT + (size_t)(j0 + ta * 16 + rowi) * 64 +
                                     ks * 32 + q * 8);
        for (int tb = 0; tb < 2; ++tb)
            bb[tb] = *(const bf16x8*)(ybf + (size_t)(b0w + tb * 16 + rowi) * 64 +
                                      ks * 32 + q * 8);
        for (int ta = 0; ta < 4; ++ta)
            for (int tb = 0; tb < 2; ++tb)
                acc[ta][tb] = __builtin_amdgcn_mfma_f32_16x16x32_bf16(
                    a[ta], bb[tb], acc[ta][tb], 0, 0, 0);
    }
    for (int ta = 0; ta < 4; ++ta)
        for (int tb = 0; tb < 2; ++tb) {
            int bl = wave * 32 + tb * 16 + rowi;      // local b in [0,128)
            int jl = ta * 16 + q * 4;
            uint_t lo = (uint_t)f2b(acc[ta][tb][0]) | ((uint_t)f2b(acc[ta][tb][1]) << 16);
            uint_t hi = (uint_t)f2b(acc[ta][tb][2]) | ((uint_t)f2b(acc[ta][tb][3]) << 16);
            int idx = bl * 72 + ((((jl >> 3) + 2 * bl) & 7) << 3) + (jl & 7);
            *(uint2*)&Ls[idx] = make_uint2(lo, hi);
        }
    __syncthreads();
    for (int pass = 0; pass < 4; ++pass) {
        int b = pass * 32 + (tid >> 3);               // local b
        int ch = tid & 7;
        uint4 v = *(const uint4*)&Ls[b * 72 + ch * 8];
        int x = (ch - 2 * b) & 7;
        *(uint4*)(Tbf + (size_t)(bt * 128 + b) * 32768 + j0 + x * 8) = v;
    }
}

// --- Krylov: per (b,k); T in registers; grad mode writes O over T. ---------
template <int NT>
__global__ __launch_bounds__(256) void krylov_k(ushort_t* __restrict__ Tbf,
                                                const float* __restrict__ z0,
                                                const float* __restrict__ z1,
                                                float* __restrict__ out) {
    __shared__ float V[NT][64];
    __shared__ float U[NT][64];
    __shared__ float zz[64];
    int bid = blockIdx.x;
    int b = bid >> 3, k = bid & 7;
    int tid = threadIdx.x;
    int row = tid >> 2, p = tid & 3, c0 = p * 16;
    bool grad = (out == nullptr);

    const ushort_t* tbase = Tbf + (size_t)bid * 4096;
    float rowT[16];
    {
        uint4 ra = *(const uint4*)(tbase + row * 64 + c0);
        uint4 rb = *(const uint4*)(tbase + row * 64 + c0 + 8);
        uint_t wv[8] = {ra.x, ra.y, ra.z, ra.w, rb.x, rb.y, rb.z, rb.w};
        for (int i = 0; i < 8; ++i) {
            rowT[2 * i]     = __uint_as_float(wv[i] << 16);
            rowT[2 * i + 1] = __uint_as_float(wv[i] & 0xFFFF0000u);
        }
    }
    float colT[16];
    if (grad) {
#pragma unroll
        for (int i = 0; i < 16; ++i) colT[i] = b2f(tbase[(c0 + i) * 64 + row]);
    }
    if (tid < 64) {
        V[0][tid] = z0[(size_t)b * 512 + k * 64 + tid];
        zz[tid]   = z1[(size_t)b * 512 + k * 64 + tid];
    }
    __syncthreads();

    for (int l = 1; l < NT; ++l) {
        const f32x4* vp = (const f32x4*)&V[l - 1][c0];
        f32x4 v0 = vp[0], v1 = vp[1], v2 = vp[2], v3 = vp[3];
        float s0 = 0.f, s1 = 0.f, s2 = 0.f, s3 = 0.f;
#pragma unroll
        for (int i = 0; i < 4; ++i) {
            s0 = fmaf(rowT[i], v0[i], s0);
            s1 = fmaf(rowT[4 + i], v1[i], s1);
            s2 = fmaf(rowT[8 + i], v2[i], s2);
            s3 = fmaf(rowT[12 + i], v3[i], s3);
        }
        float s = qsum4((s0 + s1) + (s2 + s3));
        if (p == 0) V[l][row] = s;
        __syncthreads();
    }

    if (!grad) {
        if (tid < 64) {
            float zh = 0.f;
#pragma unroll
            for (int l = 0; l < NT; ++l) zh = fmaf(INVF[l], V[l][tid], zh);
            out[(size_t)b * 512 + k * 64 + tid] = zh;
        }
        return;
    }

    if (tid < 64) {
        float zh = 0.f;
#pragma unroll
        for (int l = 0; l < NT; ++l) zh = fmaf(INVF[l], V[l][tid], zh);
        U[0][tid] = zh - zz[tid];
    }
    __syncthreads();

    for (int j = 1; j < NT; ++j) {
        const f32x4* up = (const f32x4*)&U[j - 1][c0];
        f32x4 u0 = up[0], u1 = up[1], u2 = up[2], u3 = up[3];
        float s0 = 0.f, s1 = 0.f, s2 = 0.f, s3 = 0.f;
#pragma unroll
        for (int i = 0; i < 4; ++i) {
            s0 = fmaf(colT[i], u0[i], s0);
            s1 = fmaf(colT[4 + i], u1[i], s1);
            s2 = fmaf(colT[8 + i], u2[i], s2);
            s3 = fmaf(colT[12 + i], u3[i], s3);
        }
        float s = qsum4((s0 + s1) + (s2 + s3));
        if (p == 0) U[j][row] = s;
        __syncthreads();
    }

    float W[NT];
#pragma unroll
    for (int l = 0; l < NT; ++l) {
        float w = 0.f;
#pragma unroll
        for (int j = 0; j < NT; ++j) w = fmaf(INVF[j + l + 1], U[j][row], w);
        W[l] = w;
    }
    float o[16];
#pragma unroll
    for (int i = 0; i < 16; ++i) o[i] = 0.f;
#pragma unroll
    for (int l = 0; l < NT; ++l) {
        const f32x4* vp = (const f32x4*)&V[l][c0];
        f32x4 a0 = vp[0], a1 = vp[1], a2 = vp[2], a3 = vp[3];
        float w = W[l];
#pragma unroll
        for (int i = 0; i < 4; ++i) {
            o[i]      = fmaf(w, a0[i], o[i]);
            o[4 + i]  = fmaf(w, a1[i], o[4 + i]);
            o[8 + i]  = fmaf(w, a2[i], o[8 + i]);
            o[12 + i] = fmaf(w, a3[i], o[12 + i]);
        }
    }
    uint_t ow[8];
#pragma unroll
    for (int i = 0; i < 8; ++i)
        ow[i] = (uint_t)f2b(o[2 * i]) | ((uint_t)f2b(o[2 * i + 1]) << 16);
    uint4* op = (uint4*)(Tbf + (size_t)bid * 4096 + row * 64 + c0);
    op[0] = make_uint4(ow[0], ow[1], ow[2], ow[3]);
    op[1] = make_uint4(ow[4], ow[5], ow[6], ow[7]);
}

// --- GEMM2: gpart[kc][b][m] = sum_{uv in chunk} O[b][.] psiB[m][.] ---------
// grid 512 = 8 bt (32 b each) x 64 kc; 4 waves split the 512-long K-chunk.
// 2 wg/CU, 8 waves/CU (was 1 wg/CU, 4 waves: latency-bound).
// Parallel per-wave LDS partials + ONE barrier (34.8 KB LDS).
__global__ __launch_bounds__(256) void gemm2_k(const ushort_t* __restrict__ Obf,
                                               const ushort_t* __restrict__ psiB,
                                               float* __restrict__ gpart) {
    __shared__ __align__(16) float Lg[4][32 * 68];    // [w][b 32][m 64] stride 68
    int bt = blockIdx.x & 7;           // 0..7 (32 b each)
    int kc = blockIdx.x >> 3;          // 0..63
    int k = kc >> 3;
    int uv0 = (kc & 7) * 512;
    int tid = threadIdx.x, wave = tid >> 6, lane = tid & 63;
    int rowi = lane & 15, q = lane >> 4;

    f32x4 acc[4][2];
    const f32x4 zero = {0.f, 0.f, 0.f, 0.f};
    for (int ta = 0; ta < 4; ++ta)
        for (int tb = 0; tb < 2; ++tb) acc[ta][tb] = zero;

    for (int ks = 0; ks < 4; ++ks) {
        int off = uv0 + wave * 128 + ks * 32 + q * 8;
        bf16x8 a[4], bb[2];
        for (int ta = 0; ta < 4; ++ta)
            a[ta] = *(const bf16x8*)(psiB + (size_t)k * 262144 +
                                     (size_t)(ta * 16 + rowi) * 4096 + off);
        for (int tb = 0; tb < 2; ++tb)
            bb[tb] = *(const bf16x8*)(Obf +
                                      (size_t)(bt * 32 + tb * 16 + rowi) * 32768 +
                                      k * 4096 + off);
        for (int ta = 0; ta < 4; ++ta)
            for (int tb = 0; tb < 2; ++tb)
                acc[ta][tb] = __builtin_amdgcn_mfma_f32_16x16x32_bf16(
                    a[ta], bb[tb], acc[ta][tb], 0, 0, 0);
    }
    float* lw = &Lg[wave][0];
    for (int ta = 0; ta < 4; ++ta)
        for (int tb = 0; tb < 2; ++tb)
            *(f32x4*)&lw[(tb * 16 + rowi) * 68 + ta * 16 + q * 4] = acc[ta][tb];
    __syncthreads();

    // reduce 4 wave partials: 32 b x 64 m, 8 floats per thread
    int b = tid >> 3, m0 = (tid & 7) * 8;
    const float* l0 = &Lg[0][b * 68 + m0];
    float* gp = gpart + (size_t)kc * 16384 + (size_t)(bt * 32 + b) * 64 + m0;
#pragma unroll
    for (int i = 0; i < 2; ++i) {
        f32x4 s0 = *(const f32x4*)(l0 + 4 * i);
        f32x4 s1 = *(const f32x4*)(l0 + 2176 + 4 * i);
        f32x4 s2 = *(const f32x4*)(l0 + 4352 + 4 * i);
        f32x4 s3 = *(const f32x4*)(l0 + 6528 + 4 * i);
        f32x4 s = (s0 + s1) + (s2 + s3);
        *(f32x4*)(gp + 4 * i) = s;
    }
}

// --- FISTA: reduce 64 partials + prox step; maintain fp32 + bf16 state -----
__global__ __launch_bounds__(256) void fista_update(const float* __restrict__ gpart,
                                                    float* __restrict__ cb,
                                                    float* __restrict__ yb,
                                                    ushort_t* __restrict__ cbf,
                                                    ushort_t* __restrict__ ybf,
                                                    int iter) {
    int idx = blockIdx.x * 256 + threadIdx.x;
    float a0 = 0.f, a1 = 0.f, a2 = 0.f, a3 = 0.f;
#pragma unroll
    for (int p = 0; p < 64; p += 4) {
        a0 += gpart[(size_t)p * 16384 + idx];
        a1 += gpart[(size_t)(p + 1) * 16384 + idx];
        a2 += gpart[(size_t)(p + 2) * 16384 + idx];
        a3 += gpart[(size_t)(p + 3) * 16384 + idx];
    }
    float gv = (a0 + a1) + (a2 + a3);
    float t = 1.f;
    for (int s = 0; s < iter; ++s) t = 0.5f * (1.f + sqrtf(1.f + 4.f * t * t));
    float tn = 0.5f * (1.f + sqrtf(1.f + 4.f * t * t));
    float beta = (t - 1.f) / tn;
    float co = cb[idx], yo = yb[idx];
    float a = yo - 0.01f * gv;
    float thr = 0.01f * 0.05f;
    float cn = copysignf(fmaxf(fabsf(a) - thr, 0.f), a);
    float yn = cn + beta * (cn - co);
    cb[idx] = cn;
    yb[idx] = yn;
    cbf[idx] = f2b(cn);
    ybf[idx] = f2b(yn);
}

extern "C" void kernel_launch(void* const* d_in, const int* in_sizes, int n_in,
                              void* d_out, int out_size, void* d_ws, size_t ws_size,
                              hipStream_t stream) {
    const float* z0 = (const float*)d_in[0];
    const float* z1 = (const float*)d_in[1];
    const float* psi = (const float*)d_in[2];
    float* out = (float*)d_out;

    char* w = (char*)d_ws;
    ushort_t* TO    = (ushort_t*)(w);                 // 16,777,216  (T, then O)
    ushort_t* psiB  = (ushort_t*)(w + 16777216);      //  4,194,304
    ushort_t* psiT  = (ushort_t*)(w + 20971520);      //  4,194,304
    float*    gpart = (float*)(w + 25165824);         //  4,194,304  (64 partials)
    float*    cbuf  = (float*)(w + 29360128);         //     65,536
    float*    ybuf  = (float*)(w + 29425664);         //     65,536
    ushort_t* cbf   = (ushort_t*)(w + 29491200);      //     32,768
    ushort_t* ybf   = (ushort_t*)(w + 29523968);      //     32,768
    // total 29,556,736 B

    // prep converts psi AND zeroes c/y state (196608 B) -- no memset node
    prep_k<<<1024, 256, 0, stream>>>(psi, psiB, psiT, (uint4*)(w + 29360128));

    for (int it = 0; it < 20; ++it) {
        gemm1_k<<<1024, 256, 0, stream>>>(ybf, psiT, TO);
        krylov_k<5><<<2048, 256, 0, stream>>>(TO, z0, z1, nullptr);
        gemm2_k<<<512, 256, 0, stream>>>(TO, psiB, gpart);
        fista_update<<<64, 256, 0, stream>>>(gpart, cbuf, ybuf, cbf, ybf, it);
    }

    gemm1_k<<<1024, 256, 0, stream>>>(cbf, psiT, TO);
    krylov_k<8><<<2048, 256, 0, stream>>>(TO, z0, z1, out);
}